// Round 1
// baseline (538.271 us; speedup 1.0000x reference)
//
#include <hip/hip_runtime.h>
#include <math.h>

typedef unsigned int u32;

#define N_ROWS 1000000      // N
#define NQ     N_ROWS       // float4 quads per (b) slice and per std array
#define KRANK  499999u      // (N-1)/2
#define BINS1  2048         // top 11 bits
#define BINS2  4096         // mid 12 bits
#define BINS3  512          // low 9 bits
#define BPS_MED 128
#define BPS_P   128

// ---- ws layout (bytes) ----
#define OFF_STD     0                       // 4M floats = 16,000,000
#define OFF_H1      16000000                // 24*2048*4 = 196,608
#define OFF_H2      16196608                // 24*4096*4 = 393,216
#define OFF_H3      16589824                // 24*512*4  = 49,152
#define OFF_SEL1    16638976                // 24*4
#define OFF_KREM1   16639072                // 24*4
#define OFF_PSEL    16639168                // 24*4
#define OFF_KREM2   16639264                // 24*4
#define OFF_SELVAL  16639360                // 24*4
#define OFF_TABLE   16639456                // 640*4 = 2560
#define HIST_ZERO_BYTES (OFF_SEL1 - OFF_H1) // 638,976

__device__ __forceinline__ u32 fkey(float x) {
  u32 b = __float_as_uint(x);
  return (b & 0x80000000u) ? ~b : (b | 0x80000000u);
}
__device__ __forceinline__ float funkey(u32 u) {
  u32 b = (u & 0x80000000u) ? (u & 0x7fffffffu) : ~u;
  return __uint_as_float(b);
}

// K0: 16-pattern x 10-batch x 4 output table. out only depends on mode pattern.
__global__ void k_table(const float* __restrict__ x, const float* __restrict__ dptr,
                        float* __restrict__ table) {
  int t = threadIdx.x;
  if (t >= 160) return;
  int pat = t / 10, b = t % 10;
  float delta = *dptr;
  float xs[4];
  xs[0] = 0.f; xs[1] = x[b*3]; xs[2] = x[b*3+1]; xs[3] = x[b*3+2];
  float dx[4];
  #pragma unroll
  for (int j = 0; j < 4; ++j) dx[j] = delta * (float)((pat >> j) & 1) + xs[j];
  #pragma unroll
  for (int i = 0; i < 4; ++i) {
    float m = -1e30f;
    #pragma unroll
    for (int j = 0; j < 4; ++j) if (j != i) m = fmaxf(m, dx[j]);
    float ssum = 0.f;
    #pragma unroll
    for (int j = 0; j < 4; ++j) if (j != i) ssum += expf(dx[j] - m);
    table[(pat*10 + b)*4 + i] = dx[i] - (logf(ssum) + m);
  }
}

// K1: std over b (ddof=1) for all (n,i); also level-1 histogram of std (groups 20..23).
__global__ __launch_bounds__(256) void k_std(const float* __restrict__ logits,
                                             float* __restrict__ stdv,
                                             u32* __restrict__ hist1) {
  __shared__ u32 h[4 * BINS1];
  for (int i = threadIdx.x; i < 4 * BINS1; i += 256) h[i] = 0;
  __syncthreads();
  const float4* L = (const float4*)logits;
  float4* S = (float4*)stdv;
  for (int q = blockIdx.x * 256 + threadIdx.x; q < NQ; q += gridDim.x * 256) {
    float4 v[10];
    #pragma unroll
    for (int b = 0; b < 10; ++b) v[b] = L[b * NQ + q];
    float4 r;
    #pragma unroll
    for (int j = 0; j < 4; ++j) {
      float sum = 0.f;
      #pragma unroll
      for (int b = 0; b < 10; ++b) sum = __fadd_rn(sum, ((const float*)&v[b])[j]);
      float mean = __fdiv_rn(sum, 10.0f);
      float ssd = 0.f;
      #pragma unroll
      for (int b = 0; b < 10; ++b) {
        float d = __fsub_rn(((const float*)&v[b])[j], mean);
        ssd = __fadd_rn(ssd, __fmul_rn(d, d));
      }
      float sd = sqrtf(__fdiv_rn(ssd, 9.0f));
      ((float*)&r)[j] = sd;
      atomicAdd(&h[j * BINS1 + (fkey(sd) >> 21)], 1u);
    }
    S[q] = r;
  }
  __syncthreads();
  for (int i = threadIdx.x; i < 4 * BINS1; i += 256) {
    u32 c = h[i];
    if (c) atomicAdd(&hist1[(20 + (i >> 11)) * BINS1 + (i & (BINS1 - 1))], c);
  }
}

// K2: level-1 histogram of logits for b<5 (groups b*4+i).
__global__ __launch_bounds__(256) void k_medhist(const float* __restrict__ logits,
                                                 u32* __restrict__ hist1) {
  __shared__ u32 h[4 * BINS1];
  for (int i = threadIdx.x; i < 4 * BINS1; i += 256) h[i] = 0;
  __syncthreads();
  int b = blockIdx.x / BPS_MED;
  int r = blockIdx.x % BPS_MED;
  const float4* L = (const float4*)logits + b * NQ;
  for (int q = r * 256 + threadIdx.x; q < NQ; q += BPS_MED * 256) {
    float4 v = L[q];
    atomicAdd(&h[0 * BINS1 + (fkey(v.x) >> 21)], 1u);
    atomicAdd(&h[1 * BINS1 + (fkey(v.y) >> 21)], 1u);
    atomicAdd(&h[2 * BINS1 + (fkey(v.z) >> 21)], 1u);
    atomicAdd(&h[3 * BINS1 + (fkey(v.w) >> 21)], 1u);
  }
  __syncthreads();
  int gb = b * 4;
  for (int i = threadIdx.x; i < 4 * BINS1; i += 256) {
    u32 c = h[i];
    if (c) atomicAdd(&hist1[(gb + (i >> 11)) * BINS1 + (i & (BINS1 - 1))], c);
  }
}

// Filter pass: histogram next radix digit among elements matching the selected prefix.
__global__ __launch_bounds__(256) void k_filter(const float* __restrict__ logits,
                                                const float* __restrict__ stdv,
                                                const u32* __restrict__ sel,
                                                u32* __restrict__ hist,
                                                int matchShift, int binShift, u32 binMask,
                                                int nbins) {
  int blk = blockIdx.x;
  const float4* src;
  int gb, r;
  if (blk < 5 * BPS_P) {
    int b = blk / BPS_P; r = blk % BPS_P;
    src = (const float4*)logits + b * NQ; gb = b * 4;
  } else {
    r = blk - 5 * BPS_P;
    src = (const float4*)stdv; gb = 20;
  }
  u32 s0 = sel[gb], s1 = sel[gb+1], s2 = sel[gb+2], s3 = sel[gb+3];
  for (int q = r * 256 + threadIdx.x; q < NQ; q += BPS_P * 256) {
    float4 v = src[q];
    u32 u;
    u = fkey(v.x); if ((u >> matchShift) == s0) atomicAdd(&hist[(gb+0)*nbins + ((u >> binShift) & binMask)], 1u);
    u = fkey(v.y); if ((u >> matchShift) == s1) atomicAdd(&hist[(gb+1)*nbins + ((u >> binShift) & binMask)], 1u);
    u = fkey(v.z); if ((u >> matchShift) == s2) atomicAdd(&hist[(gb+2)*nbins + ((u >> binShift) & binMask)], 1u);
    u = fkey(v.w); if ((u >> matchShift) == s3) atomicAdd(&hist[(gb+3)*nbins + ((u >> binShift) & binMask)], 1u);
  }
}

// Scan a per-group histogram, find bin containing rank k, emit selection / final value.
__global__ void k_scan(const u32* __restrict__ hist, int nbins, int level,
                       const u32* __restrict__ kin, u32* __restrict__ kout,
                       const u32* __restrict__ psel_in, u32* __restrict__ psel_out,
                       float* __restrict__ selval) {
  int g = blockIdx.x;
  int t = threadIdx.x;
  const u32* h = hist + g * nbins;
  int seg = nbins >> 8;
  u32 part = 0;
  for (int s = 0; s < seg; ++s) part += h[t * seg + s];
  __shared__ u32 sd[256];
  sd[t] = part;
  __syncthreads();
  for (int off = 1; off < 256; off <<= 1) {
    u32 x = 0;
    if (t >= off) x = sd[t - off];
    __syncthreads();
    sd[t] += x;
    __syncthreads();
  }
  u32 incl = sd[t];
  u32 excl = incl - part;
  u32 k = (level == 1) ? KRANK : kin[g];
  if (k >= excl && k < incl) {
    u32 cum = excl;
    for (int s = 0; s < seg; ++s) {
      u32 c = h[t * seg + s];
      if (k < cum + c) {
        int bin = t * seg + s;
        if (level == 1)      { psel_out[g] = (u32)bin;                          kout[g] = k - cum; }
        else if (level == 2) { psel_out[g] = (psel_in[g] << 12) | (u32)bin;     kout[g] = k - cum; }
        else                 { u32 u = (psel_in[g] << 9) | (u32)bin; selval[g] = funkey(u); }
        break;
      }
      cum += c;
    }
  }
}

// K8: fused mode + out + c. out via 16-entry pattern table; c = mode broadcast.
__global__ __launch_bounds__(256) void k_final(const float* __restrict__ logits,
                                               const float* __restrict__ selval,
                                               const float* __restrict__ table,
                                               const float* __restrict__ dptr,
                                               float* __restrict__ out) {
  __shared__ float thrA[20], thrB[20];
  __shared__ float4 tab[160];
  int t = threadIdx.x;
  if (t < 20) {
    float m  = selval[t];
    float sm = selval[20 + (t & 3)];
    thrA[t] = __fadd_rn(m, __fmul_rn(1.96f, sm));     // med + FACTOR*std_med (two roundings, no FMA)
    thrB[t] = __fadd_rn(m, __fmul_rn(0.5f, *dptr));   // med + delta/2
  }
  if (t < 160) tab[t] = ((const float4*)table)[t];
  __syncthreads();
  const float4* L = (const float4*)logits;
  float4* O = (float4*)out;
  float4* C = O + 10 * NQ;
  for (int n = blockIdx.x * 256 + t; n < NQ; n += gridDim.x * 256) {
    int s0 = 0, s1 = 0, s2 = 0, s3 = 0;
    #pragma unroll
    for (int b = 0; b < 5; ++b) {
      float4 v = L[b * NQ + n];
      s0 += (v.x >= thrA[b*4+0] && v.x >= thrB[b*4+0]) ? 1 : 0;
      s1 += (v.y >= thrA[b*4+1] && v.y >= thrB[b*4+1]) ? 1 : 0;
      s2 += (v.z >= thrA[b*4+2] && v.z >= thrB[b*4+2]) ? 1 : 0;
      s3 += (v.w >= thrA[b*4+3] && v.w >= thrB[b*4+3]) ? 1 : 0;
    }
    int m0 = s0 >= 3, m1 = s1 >= 3, m2 = s2 >= 3, m3 = s3 >= 3;
    int pat = m0 | (m1 << 1) | (m2 << 2) | (m3 << 3);
    float4 cm = make_float4((float)m0, (float)m1, (float)m2, (float)m3);
    #pragma unroll
    for (int b = 0; b < 10; ++b) {
      O[b * NQ + n] = tab[pat * 10 + b];
      C[b * NQ + n] = cm;
    }
  }
}

extern "C" void kernel_launch(void* const* d_in, const int* in_sizes, int n_in,
                              void* d_out, int out_size, void* d_ws, size_t ws_size,
                              hipStream_t stream) {
  const float* logits = (const float*)d_in[0];
  const float* x      = (const float*)d_in[1];
  const float* dptr   = (const float*)d_in[2];
  float* out = (float*)d_out;
  char* ws = (char*)d_ws;

  float* stdv   = (float*)(ws + OFF_STD);
  u32*   h1     = (u32*)(ws + OFF_H1);
  u32*   h2     = (u32*)(ws + OFF_H2);
  u32*   h3     = (u32*)(ws + OFF_H3);
  u32*   sel1   = (u32*)(ws + OFF_SEL1);
  u32*   krem1  = (u32*)(ws + OFF_KREM1);
  u32*   psel   = (u32*)(ws + OFF_PSEL);
  u32*   krem2  = (u32*)(ws + OFF_KREM2);
  float* selval = (float*)(ws + OFF_SELVAL);
  float* table  = (float*)(ws + OFF_TABLE);

  hipMemsetAsync(ws + OFF_H1, 0, HIST_ZERO_BYTES, stream);

  k_table<<<dim3(1), dim3(192), 0, stream>>>(x, dptr, table);
  k_std<<<dim3(1024), dim3(256), 0, stream>>>(logits, stdv, h1);
  k_medhist<<<dim3(5 * BPS_MED), dim3(256), 0, stream>>>(logits, h1);
  k_scan<<<dim3(24), dim3(256), 0, stream>>>(h1, BINS1, 1, nullptr, krem1, nullptr, sel1, selval);
  k_filter<<<dim3(6 * BPS_P), dim3(256), 0, stream>>>(logits, stdv, sel1, h2, 21, 9, 0xFFFu, BINS2);
  k_scan<<<dim3(24), dim3(256), 0, stream>>>(h2, BINS2, 2, krem1, krem2, sel1, psel, selval);
  k_filter<<<dim3(6 * BPS_P), dim3(256), 0, stream>>>(logits, stdv, psel, h3, 9, 0, 0x1FFu, BINS3);
  k_scan<<<dim3(24), dim3(256), 0, stream>>>(h3, BINS3, 3, krem2, nullptr, psel, nullptr, selval);
  k_final<<<dim3(2048), dim3(256), 0, stream>>>(logits, selval, table, dptr, out);
}